// Round 11
// baseline (337.716 us; speedup 1.0000x reference)
//
#include <hip/hip_runtime.h>
#include <hip/hip_fp16.h>

// Shapes: feat0 [32,128,128,32], feat1 [32,128,32,128], feat2 [32,32,128,128]
// P = 524288 points per grid; out [3,32,P] fp32.
// Full path: minmax -> block-local counting sort (512 bins, no global
// atomics) -> fp16 transpose of feats -> sorted sample with LDS-shared
// setup (4 lanes/pt, dwordx4 gathers), COALESCED slot-ordered fp16 temp ->
// finish: gather temp by inv + identity add + [P][C]->[C][P] transpose.

#define WS_P 524288
#define NCH 32
#define NBIN 512          // 8x8x8 spatial bins
#define NBLK 256          // sort blocks per grid
#define PPB  2048         // points per sort block
#define BP   64           // points per sample block
#define NSB  (WS_P / BP)  // 8192 sample blocks per grid

__device__ __forceinline__ float ntloadf(const float* p) {
    return __builtin_nontemporal_load(p);
}
__device__ __forceinline__ void ntstoref(float* p, float v) {
    __builtin_nontemporal_store(v, p);
}

// ---- ordered-uint encoding for float atomic min/max
__device__ __forceinline__ unsigned encf(float f) {
    unsigned b = __float_as_uint(f);
    return (b & 0x80000000u) ? ~b : (b | 0x80000000u);
}
__device__ __forceinline__ float decf(unsigned u) {
    unsigned b = (u & 0x80000000u) ? (u & 0x7FFFFFFFu) : ~u;
    return __uint_as_float(b);
}

__device__ __forceinline__ int bin_of(float u) {  // u in [0,1]
    int b = (int)(u * 8.0f);
    return b < 0 ? 0 : (b > 7 ? 7 : b);
}

__global__ void init_mm_kernel(unsigned* mm) {
    int t = threadIdx.x;
    if (t < 18) mm[t] = (t & 1) ? 0u : 0xFFFFFFFFu;
}

__global__ __launch_bounds__(256) void minmax_kernel(
    const float* __restrict__ v0, const float* __restrict__ v1,
    const float* __restrict__ v2, unsigned* __restrict__ mm)
{
    const int g = blockIdx.y;
    const float* v = (g == 0) ? v0 : (g == 1) ? v1 : v2;
    const int tid = threadIdx.x;

    float mn[3] = { INFINITY, INFINITY, INFINITY };
    float mx[3] = { -INFINITY, -INFINITY, -INFINITY };

    for (int idx = blockIdx.x * 256 + tid; idx < WS_P; idx += 128 * 256) {
        #pragma unroll
        for (int k = 0; k < 3; k++) {
            float f = v[(size_t)idx * 3 + k];
            mn[k] = fminf(mn[k], f);
            mx[k] = fmaxf(mx[k], f);
        }
    }

    __shared__ float smn[3][256];
    __shared__ float smx[3][256];
    #pragma unroll
    for (int k = 0; k < 3; k++) { smn[k][tid] = mn[k]; smx[k][tid] = mx[k]; }
    __syncthreads();

    for (int s = 128; s > 0; s >>= 1) {
        if (tid < s) {
            #pragma unroll
            for (int k = 0; k < 3; k++) {
                smn[k][tid] = fminf(smn[k][tid], smn[k][tid + s]);
                smx[k][tid] = fmaxf(smx[k][tid], smx[k][tid + s]);
            }
        }
        __syncthreads();
    }

    if (tid == 0) {
        #pragma unroll
        for (int k = 0; k < 3; k++) {
            atomicMin(&mm[g * 6 + k * 2 + 0], encf(smn[k][0]));
            atomicMax(&mm[g * 6 + k * 2 + 1], encf(smx[k][0]));
        }
    }
}

// phase 1: per-block LDS histograms -> counts[g][bin][blk]
__global__ __launch_bounds__(256) void block_hist_kernel(
    const float* __restrict__ v0, const float* __restrict__ v1,
    const float* __restrict__ v2, const unsigned* __restrict__ mm,
    unsigned* __restrict__ counts)
{
    const int g = blockIdx.y;
    const int blk = blockIdx.x;
    const float* v = (g == 0) ? v0 : (g == 1) ? v1 : v2;
    const int tid = threadIdx.x;

    __shared__ unsigned h[NBIN];
    for (int i = tid; i < NBIN; i += 256) h[i] = 0u;
    __syncthreads();

    float mn[3], inv_r[3];
    #pragma unroll
    for (int k = 0; k < 3; k++) {
        mn[k] = decf(mm[g * 6 + k * 2 + 0]);
        inv_r[k] = 1.0f / (decf(mm[g * 6 + k * 2 + 1]) - mn[k]);
    }

    #pragma unroll
    for (int r = 0; r < PPB / 256; r++) {
        int p = blk * PPB + r * 256 + tid;
        float u0 = (v[(size_t)p * 3 + 0] - mn[0]) * inv_r[0];
        float u1 = (v[(size_t)p * 3 + 1] - mn[1]) * inv_r[1];
        float u2 = (v[(size_t)p * 3 + 2] - mn[2]) * inv_r[2];
        int key = (bin_of(u2) * 8 + bin_of(u1)) * 8 + bin_of(u0);
        atomicAdd(&h[key], 1u);
    }
    __syncthreads();
    for (int i = tid; i < NBIN; i += 256)
        counts[((size_t)g * NBIN + i) * NBLK + blk] = h[i];
}

// phase 2a: per-(g,bin) exclusive scan over blocks (in place), emit bin totals
__global__ __launch_bounds__(256) void scanA_kernel(
    unsigned* __restrict__ counts, unsigned* __restrict__ tot)
{
    const int bin = blockIdx.x;
    const int g = blockIdx.y;
    const int t = threadIdx.x;   // 0..255 = blk
    size_t rowo = ((size_t)g * NBIN + bin) * NBLK;

    unsigned v = counts[rowo + t];
    __shared__ unsigned s[NBLK];
    s[t] = v;
    __syncthreads();
    for (int off = 1; off < NBLK; off <<= 1) {
        unsigned x = (t >= off) ? s[t - off] : 0u;
        __syncthreads();
        s[t] += x;
        __syncthreads();
    }
    counts[rowo + t] = s[t] - v;           // exclusive over blk (bscan)
    if (t == NBLK - 1) tot[g * NBIN + bin] = s[t];
}

// phase 2b: per-grid exclusive scan over bins
__global__ void scanB_kernel(const unsigned* __restrict__ tot,
                             unsigned* __restrict__ binbase)
{
    const int g = blockIdx.x;
    const int t = threadIdx.x;   // 0..511
    unsigned v = tot[g * NBIN + t];
    __shared__ unsigned s[NBIN];
    s[t] = v;
    __syncthreads();
    for (int off = 1; off < NBIN; off <<= 1) {
        unsigned x = (t >= off) ? s[t - off] : 0u;
        __syncthreads();
        s[t] += x;
        __syncthreads();
    }
    binbase[g * NBIN + t] = s[t] - v;      // exclusive over bins
}

// phase 3: rank via LDS atomics, write rec + inv
__global__ __launch_bounds__(256) void scatter_kernel(
    const float* __restrict__ v0, const float* __restrict__ v1,
    const float* __restrict__ v2, const unsigned* __restrict__ mm,
    const unsigned* __restrict__ bscan, const unsigned* __restrict__ binbase,
    uint4* __restrict__ rec, unsigned* __restrict__ inv)
{
    const int g = blockIdx.y;
    const int blk = blockIdx.x;
    const float* v = (g == 0) ? v0 : (g == 1) ? v1 : v2;
    const int tid = threadIdx.x;

    __shared__ unsigned h[NBIN];
    for (int i = tid; i < NBIN; i += 256)
        h[i] = binbase[g * NBIN + i] + bscan[((size_t)g * NBIN + i) * NBLK + blk];
    __syncthreads();

    float mn[3], inv_r[3];
    #pragma unroll
    for (int k = 0; k < 3; k++) {
        mn[k] = decf(mm[g * 6 + k * 2 + 0]);
        inv_r[k] = 1.0f / (decf(mm[g * 6 + k * 2 + 1]) - mn[k]);
    }

    #pragma unroll
    for (int r = 0; r < PPB / 256; r++) {
        int p = blk * PPB + r * 256 + tid;
        float u0 = (v[(size_t)p * 3 + 0] - mn[0]) * inv_r[0];
        float u1 = (v[(size_t)p * 3 + 1] - mn[1]) * inv_r[1];
        float u2 = (v[(size_t)p * 3 + 2] - mn[2]) * inv_r[2];
        int key = (bin_of(u2) * 8 + bin_of(u1)) * 8 + bin_of(u0);
        unsigned pos = atomicAdd(&h[key], 1u);
        rec[(size_t)g * WS_P + pos] =
            make_uint4(__float_as_uint(u0 * 2.0f - 1.0f),
                       __float_as_uint(u1 * 2.0f - 1.0f),
                       __float_as_uint(u2 * 2.0f - 1.0f), (unsigned)p);
        inv[(size_t)g * WS_P + p] = pos;
    }
}

// [C][N] fp32 -> [N][C] fp16 transpose, 32x32 tiles via LDS.
__global__ __launch_bounds__(256) void transpose16_kernel(
    const float* __restrict__ f0, const float* __restrict__ f1,
    const float* __restrict__ f2,
    __half* __restrict__ t0, __half* __restrict__ t1, __half* __restrict__ t2)
{
    const int j = blockIdx.y;
    const float* in = (j == 0) ? f0 : (j == 1) ? f1 : f2;
    __half* out = (j == 0) ? t0 : (j == 1) ? t1 : t2;

    __shared__ float tile[32][33];
    const int tx = threadIdx.x;   // 0..31
    const int ty = threadIdx.y;   // 0..7
    const int n0 = blockIdx.x * 32;

    #pragma unroll
    for (int r = 0; r < 4; r++) {
        int c = ty + r * 8;
        tile[c][tx] = ntloadf(&in[(size_t)c * WS_P + n0 + tx]);
    }
    __syncthreads();

    __half2* out2 = reinterpret_cast<__half2*>(out);
    const int tid = ty * 32 + tx;
    const int cp = tid & 15;
    #pragma unroll
    for (int r = 0; r < 2; r++) {
        int pl = (tid >> 4) + r * 16;
        float a = tile[cp * 2 + 0][pl];
        float b = tile[cp * 2 + 1][pl];
        out2[(size_t)(n0 + pl) * 16 + cp] = __floats2half2_rn(a, b);
    }
}

// ---- sorted sample with LDS-shared setup. 256 thr = 64 pts x 4 lanes.
// Phase 1 (wave 0): per point, compute 16 (byte-offset, weight) pairs
// for the two foreign sources; store in LDS. Phase 2 (all): each lane
// gathers 16 x dwordx4 (8 channels) and accumulates; COALESCED write to
// temp[slot] fp16 (sorted order; finish un-permutes via inv).
template<int I>
__device__ __forceinline__ void sample_sorted_body(
    const __half* __restrict__ t0, const __half* __restrict__ t1,
    const __half* __restrict__ t2, const uint4* __restrict__ rec,
    __half* __restrict__ temps, uint2 (*ow)[17])
{
    constexpr int Dd[3] = { 128, 128, 32 };
    constexpr int Hh[3] = { 128, 32, 128 };
    constexpr int Ww[3] = { 32, 128, 128 };

    const int bid = blockIdx.x;
    const int swz = (bid & 7) * (NSB / 8) + (bid >> 3);   // XCD-contiguous
    const int tid = threadIdx.x;
    const int slot0 = swz * BP;

    if (tid < BP) {
        uint4 r = rec[(size_t)I * WS_P + slot0 + tid];
        float g0 = __uint_as_float(r.x);
        float g1 = __uint_as_float(r.y);
        float g2 = __uint_as_float(r.z);
        #pragma unroll
        for (int jj = 0; jj < 2; jj++) {
            const int j = (I + 1 + jj) % 3;
            const int W = Ww[j], H = Hh[j], D = Dd[j];

            float ix = (g0 + 1.0f) * 0.5f * (float)(W - 1);
            float iy = (g1 + 1.0f) * 0.5f * (float)(H - 1);
            float iz = (g2 + 1.0f) * 0.5f * (float)(D - 1);
            float fx = floorf(ix), fy = floorf(iy), fz = floorf(iz);
            float wx = ix - fx, wy = iy - fy, wz = iz - fz;

            int x0 = (int)fx; x0 = x0 < 0 ? 0 : (x0 > W - 1 ? W - 1 : x0);
            int y0 = (int)fy; y0 = y0 < 0 ? 0 : (y0 > H - 1 ? H - 1 : y0);
            int z0 = (int)fz; z0 = z0 < 0 ? 0 : (z0 > D - 1 ? D - 1 : z0);
            int x1 = (x0 + 1 > W - 1) ? W - 1 : x0 + 1;
            int y1 = (y0 + 1 > H - 1) ? H - 1 : y0 + 1;
            int z1 = (z0 + 1 > D - 1) ? D - 1 : z0 + 1;

            float ux = 1.0f - wx, uy = 1.0f - wy, uz = 1.0f - wz;
            float w[8] = { uz * uy * ux, uz * uy * wx, uz * wy * ux, uz * wy * wx,
                           wz * uy * ux, wz * uy * wx, wz * wy * ux, wz * wy * wx };

            int r00 = (z0 * H + y0) * W;
            int r01 = (z0 * H + y1) * W;
            int r10 = (z1 * H + y0) * W;
            int r11 = (z1 * H + y1) * W;
            int o[8] = { r00 + x0, r00 + x1, r01 + x0, r01 + x1,
                         r10 + x0, r10 + x1, r11 + x0, r11 + x1 };

            #pragma unroll
            for (int hh = 0; hh < 8; hh++)
                ow[tid][jj * 8 + hh] =
                    make_uint2((unsigned)o[hh] * 64u, __float_as_uint(w[hh]));
        }
    }
    __syncthreads();

    const int q = tid >> 2;    // point in block
    const int l = tid & 3;     // 8-channel group
    const char* sA = (const char*)((I == 0) ? t1 : (I == 1) ? t2 : t0);
    const char* sB = (const char*)((I == 0) ? t2 : (I == 1) ? t0 : t1);

    float a0 = 0.f, a1 = 0.f, a2 = 0.f, a3 = 0.f;
    float a4 = 0.f, a5 = 0.f, a6 = 0.f, a7 = 0.f;

    #pragma unroll
    for (int cn = 0; cn < 16; cn++) {
        uint2 e = ow[q][cn];
        const char* base = (cn < 8) ? sA : sB;
        uint4 d = *reinterpret_cast<const uint4*>(base + e.x + (unsigned)l * 16u);
        float w = __uint_as_float(e.y);
        float2 f0 = __half22float2(*reinterpret_cast<__half2*>(&d.x));
        float2 f1 = __half22float2(*reinterpret_cast<__half2*>(&d.y));
        float2 f2 = __half22float2(*reinterpret_cast<__half2*>(&d.z));
        float2 f3 = __half22float2(*reinterpret_cast<__half2*>(&d.w));
        a0 = fmaf(w, f0.x, a0); a1 = fmaf(w, f0.y, a1);
        a2 = fmaf(w, f1.x, a2); a3 = fmaf(w, f1.y, a3);
        a4 = fmaf(w, f2.x, a4); a5 = fmaf(w, f2.y, a5);
        a6 = fmaf(w, f3.x, a6); a7 = fmaf(w, f3.y, a7);
    }

    __half2 h0 = __floats2half2_rn(a0, a1);
    __half2 h1 = __floats2half2_rn(a2, a3);
    __half2 h2 = __floats2half2_rn(a4, a5);
    __half2 h3 = __floats2half2_rn(a6, a7);
    uint4 wv;
    wv.x = *reinterpret_cast<unsigned*>(&h0);
    wv.y = *reinterpret_cast<unsigned*>(&h1);
    wv.z = *reinterpret_cast<unsigned*>(&h2);
    wv.w = *reinterpret_cast<unsigned*>(&h3);

    // coalesced: block writes 256 x 16 B contiguous from slot0*64
    uint4* tI = reinterpret_cast<uint4*>(temps + (size_t)I * NCH * WS_P);
    tI[(size_t)(slot0 + q) * 4 + l] = wv;
}

__global__ __launch_bounds__(256, 8) void sample_all_kernel(
    const __half* __restrict__ t0, const __half* __restrict__ t1,
    const __half* __restrict__ t2, const uint4* __restrict__ rec,
    __half* __restrict__ temps)
{
    __shared__ uint2 ow[BP][17];
    switch (blockIdx.y) {
        case 0: sample_sorted_body<0>(t0, t1, t2, rec, temps, ow); break;
        case 1: sample_sorted_body<1>(t0, t1, t2, rec, temps, ow); break;
        default: sample_sorted_body<2>(t0, t1, t2, rec, temps, ow); break;
    }
}

// finish: out[I][c][p] = temp[I][inv[p]][c] + fp16(feat_I)[p][c]
__global__ __launch_bounds__(256, 8) void finish_kernel(
    const __half* __restrict__ temps, const unsigned* __restrict__ inv,
    const __half* __restrict__ t0, const __half* __restrict__ t1,
    const __half* __restrict__ t2, float* __restrict__ out)
{
    __shared__ float sb[32][33];
    const int I = blockIdx.y;
    const __half* ti = (I == 0) ? t0 : (I == 1) ? t1 : t2;
    const int tid = threadIdx.x;
    const int p0 = blockIdx.x * 32;
    const int lpt = tid >> 3;
    const int subp = tid & 7;
    const int p = p0 + lpt;

    unsigned slot = inv[(size_t)I * WS_P + p];
    const uint2* tI = reinterpret_cast<const uint2*>(temps + (size_t)I * NCH * WS_P);
    uint2 tv = tI[(size_t)slot * 8 + subp];
    float2 s0 = __half22float2(*reinterpret_cast<__half2*>(&tv.x));
    float2 s1 = __half22float2(*reinterpret_cast<__half2*>(&tv.y));
    uint2 rI = reinterpret_cast<const uint2*>(ti)[(size_t)p * 8 + subp];
    float2 i0 = __half22float2(*reinterpret_cast<__half2*>(&rI.x));
    float2 i1 = __half22float2(*reinterpret_cast<__half2*>(&rI.y));

    sb[lpt][subp * 4 + 0] = s0.x + i0.x;
    sb[lpt][subp * 4 + 1] = s0.y + i0.y;
    sb[lpt][subp * 4 + 2] = s1.x + i1.x;
    sb[lpt][subp * 4 + 3] = s1.y + i1.y;
    __syncthreads();

    float* op = out + (size_t)I * NCH * WS_P;
    #pragma unroll
    for (int it = 0; it < 4; it++) {
        int c = it * 8 + (tid >> 5);
        size_t off = (size_t)c * WS_P + p0 + (tid & 31);
        ntstoref(&op[off], sb[tid & 31][c]);
    }
}

// ---- mid-tier path: unsorted fused sample from fp16 copies (8 lanes/pt)
template<int I>
__device__ __forceinline__ float4 gather2(
    const __half* __restrict__ t0, const __half* __restrict__ t1,
    const __half* __restrict__ t2, float g0, float g1, float g2, int subp)
{
    constexpr int Dd[3] = { 128, 128, 32 };
    constexpr int Hh[3] = { 128, 32, 128 };
    constexpr int Ww[3] = { 32, 128, 128 };

    float4 acc = make_float4(0.f, 0.f, 0.f, 0.f);
    #pragma unroll
    for (int jj = 0; jj < 2; jj++) {
        const int j = (I + 1 + jj) % 3;
        const __half* src = (j == 0) ? t0 : (j == 1) ? t1 : t2;
        const int W = Ww[j], H = Hh[j], D = Dd[j];

        float ix = (g0 + 1.0f) * 0.5f * (float)(W - 1);
        float iy = (g1 + 1.0f) * 0.5f * (float)(H - 1);
        float iz = (g2 + 1.0f) * 0.5f * (float)(D - 1);
        float fx = floorf(ix), fy = floorf(iy), fz = floorf(iz);
        float wx = ix - fx, wy = iy - fy, wz = iz - fz;

        int x0 = (int)fx; x0 = x0 < 0 ? 0 : (x0 > W - 1 ? W - 1 : x0);
        int y0 = (int)fy; y0 = y0 < 0 ? 0 : (y0 > H - 1 ? H - 1 : y0);
        int z0 = (int)fz; z0 = z0 < 0 ? 0 : (z0 > D - 1 ? D - 1 : z0);
        int x1 = (x0 + 1 > W - 1) ? W - 1 : x0 + 1;
        int y1 = (y0 + 1 > H - 1) ? H - 1 : y0 + 1;
        int z1 = (z0 + 1 > D - 1) ? D - 1 : z0 + 1;

        float ux = 1.0f - wx, uy = 1.0f - wy, uz = 1.0f - wz;
        float w[8] = { uz * uy * ux, uz * uy * wx, uz * wy * ux, uz * wy * wx,
                       wz * uy * ux, wz * uy * wx, wz * wy * ux, wz * wy * wx };

        int r00 = (z0 * H + y0) * W;
        int r01 = (z0 * H + y1) * W;
        int r10 = (z1 * H + y0) * W;
        int r11 = (z1 * H + y1) * W;
        int o[8] = { r00 + x0, r00 + x1, r01 + x0, r01 + x1,
                     r10 + x0, r10 + x1, r11 + x0, r11 + x1 };

        const uint2* s8 = reinterpret_cast<const uint2*>(src);
        #pragma unroll
        for (int h = 0; h < 2; h++) {
            uint2 rA = s8[(size_t)o[h * 4 + 0] * 8 + subp];
            uint2 rB = s8[(size_t)o[h * 4 + 1] * 8 + subp];
            uint2 rC = s8[(size_t)o[h * 4 + 2] * 8 + subp];
            uint2 rD = s8[(size_t)o[h * 4 + 3] * 8 + subp];
            float wA = w[h * 4 + 0], wB = w[h * 4 + 1];
            float wC = w[h * 4 + 2], wD = w[h * 4 + 3];
            float2 a0 = __half22float2(*reinterpret_cast<__half2*>(&rA.x));
            float2 a1 = __half22float2(*reinterpret_cast<__half2*>(&rA.y));
            float2 b0 = __half22float2(*reinterpret_cast<__half2*>(&rB.x));
            float2 b1 = __half22float2(*reinterpret_cast<__half2*>(&rB.y));
            float2 c0 = __half22float2(*reinterpret_cast<__half2*>(&rC.x));
            float2 c1 = __half22float2(*reinterpret_cast<__half2*>(&rC.y));
            float2 d0 = __half22float2(*reinterpret_cast<__half2*>(&rD.x));
            float2 d1 = __half22float2(*reinterpret_cast<__half2*>(&rD.y));
            acc.x = fmaf(wA, a0.x, acc.x); acc.y = fmaf(wA, a0.y, acc.y);
            acc.z = fmaf(wA, a1.x, acc.z); acc.w = fmaf(wA, a1.y, acc.w);
            acc.x = fmaf(wB, b0.x, acc.x); acc.y = fmaf(wB, b0.y, acc.y);
            acc.z = fmaf(wB, b1.x, acc.z); acc.w = fmaf(wB, b1.y, acc.w);
            acc.x = fmaf(wC, c0.x, acc.x); acc.y = fmaf(wC, c0.y, acc.y);
            acc.z = fmaf(wC, c1.x, acc.z); acc.w = fmaf(wC, c1.y, acc.w);
            acc.x = fmaf(wD, d0.x, acc.x); acc.y = fmaf(wD, d0.y, acc.y);
            acc.z = fmaf(wD, d1.x, acc.z); acc.w = fmaf(wD, d1.y, acc.w);
        }
    }
    return acc;
}

template<int I>
__device__ __forceinline__ void sample_body(
    const __half* __restrict__ t0, const __half* __restrict__ t1,
    const __half* __restrict__ t2,
    const float* __restrict__ v0, const float* __restrict__ v1,
    const float* __restrict__ v2,
    const unsigned* __restrict__ mm, float* __restrict__ out,
    float (*sb)[33])
{
    const int tid = threadIdx.x;
    const int p = blockIdx.x * 32 + (tid >> 3);
    const int subp = tid & 7;

    const float* verts = (I == 0) ? v0 : (I == 1) ? v1 : v2;
    const __half* ti   = (I == 0) ? t0 : (I == 1) ? t1 : t2;

    float g[3];
    #pragma unroll
    for (int k = 0; k < 3; k++) {
        float mn = decf(mm[I * 6 + k * 2 + 0]);
        float mx = decf(mm[I * 6 + k * 2 + 1]);
        float vv = ntloadf(&verts[(size_t)p * 3 + k]);
        g[k] = (vv - mn) / (mx - mn) * 2.0f - 1.0f;
    }

    float4 acc = gather2<I>(t0, t1, t2, g[0], g[1], g[2], subp);
    {
        uint2 rI = reinterpret_cast<const uint2*>(ti)[(size_t)p * 8 + subp];
        float2 i0 = __half22float2(*reinterpret_cast<__half2*>(&rI.x));
        float2 i1 = __half22float2(*reinterpret_cast<__half2*>(&rI.y));
        acc.x += i0.x; acc.y += i0.y; acc.z += i1.x; acc.w += i1.y;
    }

    const int pl = tid >> 3;
    sb[pl][subp * 4 + 0] = acc.x;
    sb[pl][subp * 4 + 1] = acc.y;
    sb[pl][subp * 4 + 2] = acc.z;
    sb[pl][subp * 4 + 3] = acc.w;
    __syncthreads();

    const int p0 = blockIdx.x * 32;
    float* op = out + (size_t)I * NCH * WS_P;
    #pragma unroll
    for (int it = 0; it < 4; it++) {
        int c = it * 8 + (tid >> 5);
        size_t off = (size_t)c * WS_P + p0 + (tid & 31);
        ntstoref(&op[off], sb[tid & 31][c]);
    }
}

__global__ __launch_bounds__(256, 8) void fused_sample_kernel(
    const __half* __restrict__ t0, const __half* __restrict__ t1,
    const __half* __restrict__ t2,
    const float* __restrict__ v0, const float* __restrict__ v1,
    const float* __restrict__ v2,
    const unsigned* __restrict__ mm, float* __restrict__ out)
{
    __shared__ float sb[32][33];
    switch (blockIdx.y) {
        case 0: sample_body<0>(t0, t1, t2, v0, v1, v2, mm, out, sb); break;
        case 1: sample_body<1>(t0, t1, t2, v0, v1, v2, mm, out, sb); break;
        default: sample_body<2>(t0, t1, t2, v0, v1, v2, mm, out, sb); break;
    }
}

// lowest tier: scalar gather from original fp32 layout
template<int I>
__global__ __launch_bounds__(256) void sample_fallback_kernel(
    const float* __restrict__ f0, const float* __restrict__ f1,
    const float* __restrict__ f2,
    const float* __restrict__ v0, const float* __restrict__ v1,
    const float* __restrict__ v2,
    const unsigned* __restrict__ mm, float* __restrict__ out)
{
    constexpr int Dd[3] = { 128, 128, 32 };
    constexpr int Hh[3] = { 128, 32, 128 };
    constexpr int Ww[3] = { 32, 128, 128 };

    const int p = blockIdx.x * 256 + threadIdx.x;
    const float* verts = (I == 0) ? v0 : (I == 1) ? v1 : v2;
    const float* fi    = (I == 0) ? f0 : (I == 1) ? f1 : f2;

    float g[3];
    #pragma unroll
    for (int k = 0; k < 3; k++) {
        float mn = decf(mm[I * 6 + k * 2 + 0]);
        float mx = decf(mm[I * 6 + k * 2 + 1]);
        float vv = verts[(size_t)p * 3 + k];
        g[k] = (vv - mn) / (mx - mn) * 2.0f - 1.0f;
    }

    float acc[NCH];
    #pragma unroll
    for (int c = 0; c < NCH; c++) acc[c] = fi[(size_t)c * WS_P + p];

    #pragma unroll
    for (int jj = 0; jj < 2; jj++) {
        const int j = (I + 1 + jj) % 3;
        const float* src = (j == 0) ? f0 : (j == 1) ? f1 : f2;
        const int W = Ww[j], H = Hh[j], D = Dd[j];

        float ix = (g[0] + 1.0f) * 0.5f * (float)(W - 1);
        float iy = (g[1] + 1.0f) * 0.5f * (float)(H - 1);
        float iz = (g[2] + 1.0f) * 0.5f * (float)(D - 1);
        float fx = floorf(ix), fy = floorf(iy), fz = floorf(iz);
        float wx = ix - fx, wy = iy - fy, wz = iz - fz;

        int x0 = (int)fx; x0 = x0 < 0 ? 0 : (x0 > W - 1 ? W - 1 : x0);
        int y0 = (int)fy; y0 = y0 < 0 ? 0 : (y0 > H - 1 ? H - 1 : y0);
        int z0 = (int)fz; z0 = z0 < 0 ? 0 : (z0 > D - 1 ? D - 1 : z0);
        int x1 = (x0 + 1 > W - 1) ? W - 1 : x0 + 1;
        int y1 = (y0 + 1 > H - 1) ? H - 1 : y0 + 1;
        int z1 = (z0 + 1 > D - 1) ? D - 1 : z0 + 1;

        float ux = 1.0f - wx, uy = 1.0f - wy, uz = 1.0f - wz;
        float w[8] = { uz * uy * ux, uz * uy * wx, uz * wy * ux, uz * wy * wx,
                       wz * uy * ux, wz * uy * wx, wz * wy * ux, wz * wy * wx };

        int r00 = (z0 * H + y0) * W;
        int r01 = (z0 * H + y1) * W;
        int r10 = (z1 * H + y0) * W;
        int r11 = (z1 * H + y1) * W;
        int o[8] = { r00 + x0, r00 + x1, r01 + x0, r01 + x1,
                     r10 + x0, r10 + x1, r11 + x0, r11 + x1 };

        #pragma unroll
        for (int cn = 0; cn < 8; cn++) {
            float wt = w[cn];
            const float* sp = src + o[cn];
            #pragma unroll
            for (int c = 0; c < NCH; c++)
                acc[c] = fmaf(wt, sp[(size_t)c * WS_P], acc[c]);
        }
    }

    float* op = out + (size_t)I * NCH * WS_P + p;
    #pragma unroll
    for (int c = 0; c < NCH; c++) op[(size_t)c * WS_P] = acc[c];
}

extern "C" void kernel_launch(void* const* d_in, const int* in_sizes, int n_in,
                              void* d_out, int out_size, void* d_ws, size_t ws_size,
                              hipStream_t stream) {
    const float* f0 = (const float*)d_in[0];
    const float* f1 = (const float*)d_in[1];
    const float* f2 = (const float*)d_in[2];
    const float* v0 = (const float*)d_in[3];
    const float* v1 = (const float*)d_in[4];
    const float* v2 = (const float*)d_in[5];
    float* out = (float*)d_out;

    char* ws = (char*)d_ws;
    const size_t FEAT_ELEMS = (size_t)NCH * WS_P;        // 16 M
    const size_t MB = 1u << 20;
    unsigned* mm = (unsigned*)ws;                        // 256 B
    unsigned* tot = (unsigned*)(ws + 4096);              // 6 KB
    unsigned* binbase = (unsigned*)(ws + 16384);         // 6 KB
    __half* t0 = (__half*)(ws + MB);                     // 3 x 32 MB
    __half* t1 = t0 + FEAT_ELEMS;
    __half* t2 = t1 + FEAT_ELEMS;
    size_t off = MB + 3 * FEAT_ELEMS * sizeof(__half);
    uint4* rec = (uint4*)(ws + off);       off += 3 * (size_t)WS_P * 16;  // 24 MB
    unsigned* inv = (unsigned*)(ws + off); off += 3 * (size_t)WS_P * 4;   // 6 MB
    unsigned* counts = (unsigned*)(ws + off);
    off += (size_t)3 * NBLK * NBIN * 4;                                   // 1.5 MB
    __half* temps = (__half*)(ws + off);
    off += 3 * FEAT_ELEMS * sizeof(__half);                               // 96 MB
    const size_t FULL_NEED = off;
    const size_t MID_NEED = MB + 3 * FEAT_ELEMS * sizeof(__half);

    hipLaunchKernelGGL(init_mm_kernel, dim3(1), dim3(32), 0, stream, mm);
    hipLaunchKernelGGL(minmax_kernel, dim3(128, 3), dim3(256), 0, stream,
                       v0, v1, v2, mm);

    if (ws_size >= FULL_NEED) {
        hipLaunchKernelGGL(block_hist_kernel, dim3(NBLK, 3), dim3(256), 0, stream,
                           v0, v1, v2, mm, counts);
        hipLaunchKernelGGL(scanA_kernel, dim3(NBIN, 3), dim3(NBLK), 0, stream,
                           counts, tot);
        hipLaunchKernelGGL(scanB_kernel, dim3(3), dim3(NBIN), 0, stream,
                           tot, binbase);
        hipLaunchKernelGGL(scatter_kernel, dim3(NBLK, 3), dim3(256), 0, stream,
                           v0, v1, v2, mm, counts, binbase, rec, inv);
        hipLaunchKernelGGL(transpose16_kernel, dim3(WS_P / 32, 3), dim3(32, 8), 0,
                           stream, f0, f1, f2, t0, t1, t2);
        hipLaunchKernelGGL(sample_all_kernel, dim3(NSB, 3), dim3(256), 0,
                           stream, t0, t1, t2, rec, temps);
        hipLaunchKernelGGL(finish_kernel, dim3(WS_P / 32, 3), dim3(256), 0,
                           stream, temps, inv, t0, t1, t2, out);
    } else if (ws_size >= MID_NEED) {
        hipLaunchKernelGGL(transpose16_kernel, dim3(WS_P / 32, 3), dim3(32, 8), 0,
                           stream, f0, f1, f2, t0, t1, t2);
        hipLaunchKernelGGL(fused_sample_kernel, dim3(WS_P / 32, 3), dim3(256), 0,
                           stream, t0, t1, t2, v0, v1, v2, mm, out);
    } else {
        hipLaunchKernelGGL((sample_fallback_kernel<0>), dim3(WS_P / 256), dim3(256), 0,
                           stream, f0, f1, f2, v0, v1, v2, mm, out);
        hipLaunchKernelGGL((sample_fallback_kernel<1>), dim3(WS_P / 256), dim3(256), 0,
                           stream, f0, f1, f2, v0, v1, v2, mm, out);
        hipLaunchKernelGGL((sample_fallback_kernel<2>), dim3(WS_P / 256), dim3(256), 0,
                           stream, f0, f1, f2, v0, v1, v2, mm, out);
    }
}

// Round 12
// 286.526 us; speedup vs baseline: 1.1787x; 1.1787x over previous
//
#include <hip/hip_runtime.h>
#include <hip/hip_fp16.h>

// Shapes: feat0 [32,128,128,32], feat1 [32,128,32,128], feat2 [32,32,128,128]
// P = 524288 points per grid; out [3,32,P] fp32.
// Full path: minmax -> block-local counting sort (512 bins) -> fused
// {fp16 transpose of feats + verts histogram} -> sorted sample with
// lane-parallel LDS-shared setup + fp16 packed accumulation, scattered
// fp16 temp[p] write -> streaming finish (identity add + transpose).

#define WS_P 524288
#define NCH 32
#define NBIN 512          // 8x8x8 spatial bins
#define NBLK 256          // sort blocks per grid
#define PPB  2048         // points per sort block
#define BP   64           // points per sample block
#define NSB  (WS_P / BP)  // 8192 sample blocks per grid
#define NTB  (WS_P / 32)  // 16384 transpose tiles per grid

__device__ __forceinline__ float ntloadf(const float* p) {
    return __builtin_nontemporal_load(p);
}
__device__ __forceinline__ void ntstoref(float* p, float v) {
    __builtin_nontemporal_store(v, p);
}

// ---- ordered-uint encoding for float atomic min/max
__device__ __forceinline__ unsigned encf(float f) {
    unsigned b = __float_as_uint(f);
    return (b & 0x80000000u) ? ~b : (b | 0x80000000u);
}
__device__ __forceinline__ float decf(unsigned u) {
    unsigned b = (u & 0x80000000u) ? (u & 0x7FFFFFFFu) : ~u;
    return __uint_as_float(b);
}

__device__ __forceinline__ int bin_of(float u) {  // u in [0,1]
    int b = (int)(u * 8.0f);
    return b < 0 ? 0 : (b > 7 ? 7 : b);
}

__global__ void init_mm_kernel(unsigned* mm) {
    int t = threadIdx.x;
    if (t < 18) mm[t] = (t & 1) ? 0u : 0xFFFFFFFFu;
}

__global__ __launch_bounds__(256) void minmax_kernel(
    const float* __restrict__ v0, const float* __restrict__ v1,
    const float* __restrict__ v2, unsigned* __restrict__ mm)
{
    const int g = blockIdx.y;
    const float* v = (g == 0) ? v0 : (g == 1) ? v1 : v2;
    const int tid = threadIdx.x;

    float mn[3] = { INFINITY, INFINITY, INFINITY };
    float mx[3] = { -INFINITY, -INFINITY, -INFINITY };

    for (int idx = blockIdx.x * 256 + tid; idx < WS_P; idx += 128 * 256) {
        #pragma unroll
        for (int k = 0; k < 3; k++) {
            float f = v[(size_t)idx * 3 + k];
            mn[k] = fminf(mn[k], f);
            mx[k] = fmaxf(mx[k], f);
        }
    }

    __shared__ float smn[3][256];
    __shared__ float smx[3][256];
    #pragma unroll
    for (int k = 0; k < 3; k++) { smn[k][tid] = mn[k]; smx[k][tid] = mx[k]; }
    __syncthreads();

    for (int s = 128; s > 0; s >>= 1) {
        if (tid < s) {
            #pragma unroll
            for (int k = 0; k < 3; k++) {
                smn[k][tid] = fminf(smn[k][tid], smn[k][tid + s]);
                smx[k][tid] = fmaxf(smx[k][tid], smx[k][tid + s]);
            }
        }
        __syncthreads();
    }

    if (tid == 0) {
        #pragma unroll
        for (int k = 0; k < 3; k++) {
            atomicMin(&mm[g * 6 + k * 2 + 0], encf(smn[k][0]));
            atomicMax(&mm[g * 6 + k * 2 + 1], encf(smx[k][0]));
        }
    }
}

// fused: hist blocks (first 256 of grid.x) + fp32->fp16 transpose tiles.
__global__ __launch_bounds__(256) void transpose_hist_kernel(
    const float* __restrict__ f0, const float* __restrict__ f1,
    const float* __restrict__ f2,
    __half* __restrict__ t0, __half* __restrict__ t1, __half* __restrict__ t2,
    const float* __restrict__ v0, const float* __restrict__ v1,
    const float* __restrict__ v2, const unsigned* __restrict__ mm,
    unsigned* __restrict__ counts)
{
    __shared__ float tile[32][33];
    __shared__ unsigned h[NBIN];
    const int g = blockIdx.y;
    const int tid = threadIdx.x;

    if (blockIdx.x < NBLK) {
        // ---- histogram part
        const int blk = blockIdx.x;
        const float* v = (g == 0) ? v0 : (g == 1) ? v1 : v2;
        for (int i = tid; i < NBIN; i += 256) h[i] = 0u;
        __syncthreads();

        float mn[3], inv_r[3];
        #pragma unroll
        for (int k = 0; k < 3; k++) {
            mn[k] = decf(mm[g * 6 + k * 2 + 0]);
            inv_r[k] = 1.0f / (decf(mm[g * 6 + k * 2 + 1]) - mn[k]);
        }
        #pragma unroll
        for (int r = 0; r < PPB / 256; r++) {
            int p = blk * PPB + r * 256 + tid;
            float u0 = (v[(size_t)p * 3 + 0] - mn[0]) * inv_r[0];
            float u1 = (v[(size_t)p * 3 + 1] - mn[1]) * inv_r[1];
            float u2 = (v[(size_t)p * 3 + 2] - mn[2]) * inv_r[2];
            int key = (bin_of(u2) * 8 + bin_of(u1)) * 8 + bin_of(u0);
            atomicAdd(&h[key], 1u);
        }
        __syncthreads();
        for (int i = tid; i < NBIN; i += 256)
            counts[((size_t)g * NBIN + i) * NBLK + blk] = h[i];
    } else {
        // ---- transpose part
        const int bt = blockIdx.x - NBLK;
        const float* in = (g == 0) ? f0 : (g == 1) ? f1 : f2;
        __half* out = (g == 0) ? t0 : (g == 1) ? t1 : t2;
        const int tx = tid & 31;
        const int ty = tid >> 5;
        const int n0 = bt * 32;

        #pragma unroll
        for (int r = 0; r < 4; r++) {
            int c = ty + r * 8;
            tile[c][tx] = ntloadf(&in[(size_t)c * WS_P + n0 + tx]);
        }
        __syncthreads();

        __half2* out2 = reinterpret_cast<__half2*>(out);
        const int cp = tid & 15;
        #pragma unroll
        for (int r = 0; r < 2; r++) {
            int pl = (tid >> 4) + r * 16;
            float a = tile[cp * 2 + 0][pl];
            float b = tile[cp * 2 + 1][pl];
            out2[(size_t)(n0 + pl) * 16 + cp] = __floats2half2_rn(a, b);
        }
    }
}

// scanA: per-(g,bin) exclusive scan over blocks (in place), emit bin totals
__global__ __launch_bounds__(256) void scanA_kernel(
    unsigned* __restrict__ counts, unsigned* __restrict__ tot)
{
    const int bin = blockIdx.x;
    const int g = blockIdx.y;
    const int t = threadIdx.x;   // 0..255 = blk
    size_t rowo = ((size_t)g * NBIN + bin) * NBLK;

    unsigned v = counts[rowo + t];
    __shared__ unsigned s[NBLK];
    s[t] = v;
    __syncthreads();
    for (int off = 1; off < NBLK; off <<= 1) {
        unsigned x = (t >= off) ? s[t - off] : 0u;
        __syncthreads();
        s[t] += x;
        __syncthreads();
    }
    counts[rowo + t] = s[t] - v;           // exclusive over blk (bscan)
    if (t == NBLK - 1) tot[g * NBIN + bin] = s[t];
}

// scanB: per-grid exclusive scan over bins
__global__ void scanB_kernel(const unsigned* __restrict__ tot,
                             unsigned* __restrict__ binbase)
{
    const int g = blockIdx.x;
    const int t = threadIdx.x;   // 0..511
    unsigned v = tot[g * NBIN + t];
    __shared__ unsigned s[NBIN];
    s[t] = v;
    __syncthreads();
    for (int off = 1; off < NBIN; off <<= 1) {
        unsigned x = (t >= off) ? s[t - off] : 0u;
        __syncthreads();
        s[t] += x;
        __syncthreads();
    }
    binbase[g * NBIN + t] = s[t] - v;      // exclusive over bins
}

// rank via LDS atomics, write rec only
__global__ __launch_bounds__(256) void scatter_kernel(
    const float* __restrict__ v0, const float* __restrict__ v1,
    const float* __restrict__ v2, const unsigned* __restrict__ mm,
    const unsigned* __restrict__ bscan, const unsigned* __restrict__ binbase,
    uint4* __restrict__ rec)
{
    const int g = blockIdx.y;
    const int blk = blockIdx.x;
    const float* v = (g == 0) ? v0 : (g == 1) ? v1 : v2;
    const int tid = threadIdx.x;

    __shared__ unsigned h[NBIN];
    for (int i = tid; i < NBIN; i += 256)
        h[i] = binbase[g * NBIN + i] + bscan[((size_t)g * NBIN + i) * NBLK + blk];
    __syncthreads();

    float mn[3], inv_r[3];
    #pragma unroll
    for (int k = 0; k < 3; k++) {
        mn[k] = decf(mm[g * 6 + k * 2 + 0]);
        inv_r[k] = 1.0f / (decf(mm[g * 6 + k * 2 + 1]) - mn[k]);
    }

    #pragma unroll
    for (int r = 0; r < PPB / 256; r++) {
        int p = blk * PPB + r * 256 + tid;
        float u0 = (v[(size_t)p * 3 + 0] - mn[0]) * inv_r[0];
        float u1 = (v[(size_t)p * 3 + 1] - mn[1]) * inv_r[1];
        float u2 = (v[(size_t)p * 3 + 2] - mn[2]) * inv_r[2];
        int key = (bin_of(u2) * 8 + bin_of(u1)) * 8 + bin_of(u0);
        unsigned pos = atomicAdd(&h[key], 1u);
        rec[(size_t)g * WS_P + pos] =
            make_uint4(__float_as_uint(u0 * 2.0f - 1.0f),
                       __float_as_uint(u1 * 2.0f - 1.0f),
                       __float_as_uint(u2 * 2.0f - 1.0f), (unsigned)p);
    }
}

// ---- sorted sample. 256 thr = 64 pts x 4 lanes. Lane-parallel setup:
// lane l of point q computes source jj=l>>1, z-half b=l&1 -> 4 (off,w)
// entries into LDS. Gather: 16 x dwordx4 + packed fp16 fma; scattered
// 16 B write into temp[p] (fp16).
template<int I>
__device__ __forceinline__ void sample_sorted_body(
    const __half* __restrict__ t0, const __half* __restrict__ t1,
    const __half* __restrict__ t2, const uint4* __restrict__ rec,
    __half* __restrict__ temps, uint2 (*ow)[17], unsigned* pp)
{
    constexpr int Dd[3] = { 128, 128, 32 };
    constexpr int Hh[3] = { 128, 32, 128 };
    constexpr int Ww[3] = { 32, 128, 128 };

    const int bid = blockIdx.x;
    const int swz = (bid & 7) * (NSB / 8) + (bid >> 3);   // XCD-contiguous
    const int tid = threadIdx.x;
    const int slot0 = swz * BP;
    const int q = tid >> 2;    // point in block
    const int l = tid & 3;     // lane within point

    {
        uint4 r = rec[(size_t)I * WS_P + slot0 + q];
        if (l == 0) pp[q] = r.w;
        float g0 = __uint_as_float(r.x);
        float g1 = __uint_as_float(r.y);
        float g2 = __uint_as_float(r.z);

        const int jj = l >> 1;                 // which foreign source
        const int j = (I + 1 + jj) % 3;
        const int W = Ww[j], H = Hh[j], D = Dd[j];

        float ix = (g0 + 1.0f) * 0.5f * (float)(W - 1);
        float iy = (g1 + 1.0f) * 0.5f * (float)(H - 1);
        float iz = (g2 + 1.0f) * 0.5f * (float)(D - 1);
        float fx = floorf(ix), fy = floorf(iy), fz = floorf(iz);
        float wx = ix - fx, wy = iy - fy, wz = iz - fz;

        int x0 = (int)fx; x0 = x0 < 0 ? 0 : (x0 > W - 1 ? W - 1 : x0);
        int y0 = (int)fy; y0 = y0 < 0 ? 0 : (y0 > H - 1 ? H - 1 : y0);
        int z0 = (int)fz; z0 = z0 < 0 ? 0 : (z0 > D - 1 ? D - 1 : z0);
        int x1 = (x0 + 1 > W - 1) ? W - 1 : x0 + 1;
        int y1 = (y0 + 1 > H - 1) ? H - 1 : y0 + 1;
        int z1 = (z0 + 1 > D - 1) ? D - 1 : z0 + 1;

        float ux = 1.0f - wx, uy = 1.0f - wy, uz = 1.0f - wz;

        const int b = l & 1;                   // z-half
        int zz = b ? z1 : z0;
        float fzw = b ? wz : uz;
        int rb0 = (zz * H + y0) * W;
        int rb1 = (zz * H + y1) * W;
        unsigned o4[4] = { (unsigned)(rb0 + x0), (unsigned)(rb0 + x1),
                           (unsigned)(rb1 + x0), (unsigned)(rb1 + x1) };
        float w4[4] = { fzw * uy * ux, fzw * uy * wx,
                        fzw * wy * ux, fzw * wy * wx };

        const int basei = jj * 8 + b * 4;
        #pragma unroll
        for (int c = 0; c < 4; c++) {
            __half2 ww = __floats2half2_rn(w4[c], w4[c]);
            ow[q][basei + c] =
                make_uint2(o4[c] * 64u, *reinterpret_cast<unsigned*>(&ww));
        }
    }
    __syncthreads();

    const char* sA = (const char*)((I == 0) ? t1 : (I == 1) ? t2 : t0);
    const char* sB = (const char*)((I == 0) ? t2 : (I == 1) ? t0 : t1);

    __half2 acc0 = __floats2half2_rn(0.f, 0.f);
    __half2 acc1 = acc0, acc2 = acc0, acc3 = acc0;

    #pragma unroll
    for (int cn = 0; cn < 16; cn++) {
        uint2 e = ow[q][cn];
        const char* base = (cn < 8) ? sA : sB;
        uint4 d = *reinterpret_cast<const uint4*>(base + e.x + (unsigned)l * 16u);
        __half2 ww = *reinterpret_cast<__half2*>(&e.y);
        acc0 = __hfma2(*reinterpret_cast<__half2*>(&d.x), ww, acc0);
        acc1 = __hfma2(*reinterpret_cast<__half2*>(&d.y), ww, acc1);
        acc2 = __hfma2(*reinterpret_cast<__half2*>(&d.z), ww, acc2);
        acc3 = __hfma2(*reinterpret_cast<__half2*>(&d.w), ww, acc3);
    }

    uint4 wv;
    wv.x = *reinterpret_cast<unsigned*>(&acc0);
    wv.y = *reinterpret_cast<unsigned*>(&acc1);
    wv.z = *reinterpret_cast<unsigned*>(&acc2);
    wv.w = *reinterpret_cast<unsigned*>(&acc3);

    unsigned p = pp[q];
    char* dst = (char*)(temps + (size_t)I * NCH * WS_P) + (size_t)p * 64u;
    reinterpret_cast<uint4*>(dst)[l] = wv;
}

__global__ __launch_bounds__(256, 8) void sample_all_kernel(
    const __half* __restrict__ t0, const __half* __restrict__ t1,
    const __half* __restrict__ t2, const uint4* __restrict__ rec,
    __half* __restrict__ temps)
{
    __shared__ uint2 ow[BP][17];
    __shared__ unsigned pp[BP];
    switch (blockIdx.y) {
        case 0: sample_sorted_body<0>(t0, t1, t2, rec, temps, ow, pp); break;
        case 1: sample_sorted_body<1>(t0, t1, t2, rec, temps, ow, pp); break;
        default: sample_sorted_body<2>(t0, t1, t2, rec, temps, ow, pp); break;
    }
}

// streaming finish: out[I][c][p] = temp[I][p][c] + fp16(feat_I)[p][c]
__global__ __launch_bounds__(256, 8) void finish_kernel(
    const __half* __restrict__ temps,
    const __half* __restrict__ t0, const __half* __restrict__ t1,
    const __half* __restrict__ t2, float* __restrict__ out)
{
    __shared__ float sb[32][33];
    const int I = blockIdx.y;
    const __half* ti = (I == 0) ? t0 : (I == 1) ? t1 : t2;
    const int tid = threadIdx.x;
    const int p0 = blockIdx.x * 32;
    const int lpt = tid >> 3;
    const int subp = tid & 7;
    const int p = p0 + lpt;

    const uint2* tI = reinterpret_cast<const uint2*>(temps + (size_t)I * NCH * WS_P);
    uint2 tv = tI[(size_t)p * 8 + subp];
    float2 s0 = __half22float2(*reinterpret_cast<__half2*>(&tv.x));
    float2 s1 = __half22float2(*reinterpret_cast<__half2*>(&tv.y));
    uint2 rI = reinterpret_cast<const uint2*>(ti)[(size_t)p * 8 + subp];
    float2 i0 = __half22float2(*reinterpret_cast<__half2*>(&rI.x));
    float2 i1 = __half22float2(*reinterpret_cast<__half2*>(&rI.y));

    sb[lpt][subp * 4 + 0] = s0.x + i0.x;
    sb[lpt][subp * 4 + 1] = s0.y + i0.y;
    sb[lpt][subp * 4 + 2] = s1.x + i1.x;
    sb[lpt][subp * 4 + 3] = s1.y + i1.y;
    __syncthreads();

    float* op = out + (size_t)I * NCH * WS_P;
    #pragma unroll
    for (int it = 0; it < 4; it++) {
        int c = it * 8 + (tid >> 5);
        size_t off = (size_t)c * WS_P + p0 + (tid & 31);
        ntstoref(&op[off], sb[tid & 31][c]);
    }
}

// ---- mid-tier path: unsorted fused sample from fp16 copies (8 lanes/pt)
template<int I>
__device__ __forceinline__ float4 gather2(
    const __half* __restrict__ t0, const __half* __restrict__ t1,
    const __half* __restrict__ t2, float g0, float g1, float g2, int subp)
{
    constexpr int Dd[3] = { 128, 128, 32 };
    constexpr int Hh[3] = { 128, 32, 128 };
    constexpr int Ww[3] = { 32, 128, 128 };

    float4 acc = make_float4(0.f, 0.f, 0.f, 0.f);
    #pragma unroll
    for (int jj = 0; jj < 2; jj++) {
        const int j = (I + 1 + jj) % 3;
        const __half* src = (j == 0) ? t0 : (j == 1) ? t1 : t2;
        const int W = Ww[j], H = Hh[j], D = Dd[j];

        float ix = (g0 + 1.0f) * 0.5f * (float)(W - 1);
        float iy = (g1 + 1.0f) * 0.5f * (float)(H - 1);
        float iz = (g2 + 1.0f) * 0.5f * (float)(D - 1);
        float fx = floorf(ix), fy = floorf(iy), fz = floorf(iz);
        float wx = ix - fx, wy = iy - fy, wz = iz - fz;

        int x0 = (int)fx; x0 = x0 < 0 ? 0 : (x0 > W - 1 ? W - 1 : x0);
        int y0 = (int)fy; y0 = y0 < 0 ? 0 : (y0 > H - 1 ? H - 1 : y0);
        int z0 = (int)fz; z0 = z0 < 0 ? 0 : (z0 > D - 1 ? D - 1 : z0);
        int x1 = (x0 + 1 > W - 1) ? W - 1 : x0 + 1;
        int y1 = (y0 + 1 > H - 1) ? H - 1 : y0 + 1;
        int z1 = (z0 + 1 > D - 1) ? D - 1 : z0 + 1;

        float ux = 1.0f - wx, uy = 1.0f - wy, uz = 1.0f - wz;
        float w[8] = { uz * uy * ux, uz * uy * wx, uz * wy * ux, uz * wy * wx,
                       wz * uy * ux, wz * uy * wx, wz * wy * ux, wz * wy * wx };

        int r00 = (z0 * H + y0) * W;
        int r01 = (z0 * H + y1) * W;
        int r10 = (z1 * H + y0) * W;
        int r11 = (z1 * H + y1) * W;
        int o[8] = { r00 + x0, r00 + x1, r01 + x0, r01 + x1,
                     r10 + x0, r10 + x1, r11 + x0, r11 + x1 };

        const uint2* s8 = reinterpret_cast<const uint2*>(src);
        #pragma unroll
        for (int h = 0; h < 2; h++) {
            uint2 rA = s8[(size_t)o[h * 4 + 0] * 8 + subp];
            uint2 rB = s8[(size_t)o[h * 4 + 1] * 8 + subp];
            uint2 rC = s8[(size_t)o[h * 4 + 2] * 8 + subp];
            uint2 rD = s8[(size_t)o[h * 4 + 3] * 8 + subp];
            float wA = w[h * 4 + 0], wB = w[h * 4 + 1];
            float wC = w[h * 4 + 2], wD = w[h * 4 + 3];
            float2 a0 = __half22float2(*reinterpret_cast<__half2*>(&rA.x));
            float2 a1 = __half22float2(*reinterpret_cast<__half2*>(&rA.y));
            float2 b0 = __half22float2(*reinterpret_cast<__half2*>(&rB.x));
            float2 b1 = __half22float2(*reinterpret_cast<__half2*>(&rB.y));
            float2 c0 = __half22float2(*reinterpret_cast<__half2*>(&rC.x));
            float2 c1 = __half22float2(*reinterpret_cast<__half2*>(&rC.y));
            float2 d0 = __half22float2(*reinterpret_cast<__half2*>(&rD.x));
            float2 d1 = __half22float2(*reinterpret_cast<__half2*>(&rD.y));
            acc.x = fmaf(wA, a0.x, acc.x); acc.y = fmaf(wA, a0.y, acc.y);
            acc.z = fmaf(wA, a1.x, acc.z); acc.w = fmaf(wA, a1.y, acc.w);
            acc.x = fmaf(wB, b0.x, acc.x); acc.y = fmaf(wB, b0.y, acc.y);
            acc.z = fmaf(wB, b1.x, acc.z); acc.w = fmaf(wB, b1.y, acc.w);
            acc.x = fmaf(wC, c0.x, acc.x); acc.y = fmaf(wC, c0.y, acc.y);
            acc.z = fmaf(wC, c1.x, acc.z); acc.w = fmaf(wC, c1.y, acc.w);
            acc.x = fmaf(wD, d0.x, acc.x); acc.y = fmaf(wD, d0.y, acc.y);
            acc.z = fmaf(wD, d1.x, acc.z); acc.w = fmaf(wD, d1.y, acc.w);
        }
    }
    return acc;
}

template<int I>
__device__ __forceinline__ void sample_body(
    const __half* __restrict__ t0, const __half* __restrict__ t1,
    const __half* __restrict__ t2,
    const float* __restrict__ v0, const float* __restrict__ v1,
    const float* __restrict__ v2,
    const unsigned* __restrict__ mm, float* __restrict__ out,
    float (*sb)[33])
{
    const int tid = threadIdx.x;
    const int p = blockIdx.x * 32 + (tid >> 3);
    const int subp = tid & 7;

    const float* verts = (I == 0) ? v0 : (I == 1) ? v1 : v2;
    const __half* ti   = (I == 0) ? t0 : (I == 1) ? t1 : t2;

    float g[3];
    #pragma unroll
    for (int k = 0; k < 3; k++) {
        float mn = decf(mm[I * 6 + k * 2 + 0]);
        float mx = decf(mm[I * 6 + k * 2 + 1]);
        float vv = ntloadf(&verts[(size_t)p * 3 + k]);
        g[k] = (vv - mn) / (mx - mn) * 2.0f - 1.0f;
    }

    float4 acc = gather2<I>(t0, t1, t2, g[0], g[1], g[2], subp);
    {
        uint2 rI = reinterpret_cast<const uint2*>(ti)[(size_t)p * 8 + subp];
        float2 i0 = __half22float2(*reinterpret_cast<__half2*>(&rI.x));
        float2 i1 = __half22float2(*reinterpret_cast<__half2*>(&rI.y));
        acc.x += i0.x; acc.y += i0.y; acc.z += i1.x; acc.w += i1.y;
    }

    const int pl = tid >> 3;
    sb[pl][subp * 4 + 0] = acc.x;
    sb[pl][subp * 4 + 1] = acc.y;
    sb[pl][subp * 4 + 2] = acc.z;
    sb[pl][subp * 4 + 3] = acc.w;
    __syncthreads();

    const int p0 = blockIdx.x * 32;
    float* op = out + (size_t)I * NCH * WS_P;
    #pragma unroll
    for (int it = 0; it < 4; it++) {
        int c = it * 8 + (tid >> 5);
        size_t off = (size_t)c * WS_P + p0 + (tid & 31);
        ntstoref(&op[off], sb[tid & 31][c]);
    }
}

__global__ __launch_bounds__(256, 8) void fused_sample_kernel(
    const __half* __restrict__ t0, const __half* __restrict__ t1,
    const __half* __restrict__ t2,
    const float* __restrict__ v0, const float* __restrict__ v1,
    const float* __restrict__ v2,
    const unsigned* __restrict__ mm, float* __restrict__ out)
{
    __shared__ float sb[32][33];
    switch (blockIdx.y) {
        case 0: sample_body<0>(t0, t1, t2, v0, v1, v2, mm, out, sb); break;
        case 1: sample_body<1>(t0, t1, t2, v0, v1, v2, mm, out, sb); break;
        default: sample_body<2>(t0, t1, t2, v0, v1, v2, mm, out, sb); break;
    }
}

// transpose-only kernel for the mid tier (no hist)
__global__ __launch_bounds__(256) void transpose16_kernel(
    const float* __restrict__ f0, const float* __restrict__ f1,
    const float* __restrict__ f2,
    __half* __restrict__ t0, __half* __restrict__ t1, __half* __restrict__ t2)
{
    const int j = blockIdx.y;
    const float* in = (j == 0) ? f0 : (j == 1) ? f1 : f2;
    __half* out = (j == 0) ? t0 : (j == 1) ? t1 : t2;

    __shared__ float tile[32][33];
    const int tid = threadIdx.x;
    const int tx = tid & 31;
    const int ty = tid >> 5;
    const int n0 = blockIdx.x * 32;

    #pragma unroll
    for (int r = 0; r < 4; r++) {
        int c = ty + r * 8;
        tile[c][tx] = ntloadf(&in[(size_t)c * WS_P + n0 + tx]);
    }
    __syncthreads();

    __half2* out2 = reinterpret_cast<__half2*>(out);
    const int cp = tid & 15;
    #pragma unroll
    for (int r = 0; r < 2; r++) {
        int pl = (tid >> 4) + r * 16;
        float a = tile[cp * 2 + 0][pl];
        float b = tile[cp * 2 + 1][pl];
        out2[(size_t)(n0 + pl) * 16 + cp] = __floats2half2_rn(a, b);
    }
}

// lowest tier: scalar gather from original fp32 layout
template<int I>
__global__ __launch_bounds__(256) void sample_fallback_kernel(
    const float* __restrict__ f0, const float* __restrict__ f1,
    const float* __restrict__ f2,
    const float* __restrict__ v0, const float* __restrict__ v1,
    const float* __restrict__ v2,
    const unsigned* __restrict__ mm, float* __restrict__ out)
{
    constexpr int Dd[3] = { 128, 128, 32 };
    constexpr int Hh[3] = { 128, 32, 128 };
    constexpr int Ww[3] = { 32, 128, 128 };

    const int p = blockIdx.x * 256 + threadIdx.x;
    const float* verts = (I == 0) ? v0 : (I == 1) ? v1 : v2;
    const float* fi    = (I == 0) ? f0 : (I == 1) ? f1 : f2;

    float g[3];
    #pragma unroll
    for (int k = 0; k < 3; k++) {
        float mn = decf(mm[I * 6 + k * 2 + 0]);
        float mx = decf(mm[I * 6 + k * 2 + 1]);
        float vv = verts[(size_t)p * 3 + k];
        g[k] = (vv - mn) / (mx - mn) * 2.0f - 1.0f;
    }

    float acc[NCH];
    #pragma unroll
    for (int c = 0; c < NCH; c++) acc[c] = fi[(size_t)c * WS_P + p];

    #pragma unroll
    for (int jj = 0; jj < 2; jj++) {
        const int j = (I + 1 + jj) % 3;
        const float* src = (j == 0) ? f0 : (j == 1) ? f1 : f2;
        const int W = Ww[j], H = Hh[j], D = Dd[j];

        float ix = (g[0] + 1.0f) * 0.5f * (float)(W - 1);
        float iy = (g[1] + 1.0f) * 0.5f * (float)(H - 1);
        float iz = (g[2] + 1.0f) * 0.5f * (float)(D - 1);
        float fx = floorf(ix), fy = floorf(iy), fz = floorf(iz);
        float wx = ix - fx, wy = iy - fy, wz = iz - fz;

        int x0 = (int)fx; x0 = x0 < 0 ? 0 : (x0 > W - 1 ? W - 1 : x0);
        int y0 = (int)fy; y0 = y0 < 0 ? 0 : (y0 > H - 1 ? H - 1 : y0);
        int z0 = (int)fz; z0 = z0 < 0 ? 0 : (z0 > D - 1 ? D - 1 : z0);
        int x1 = (x0 + 1 > W - 1) ? W - 1 : x0 + 1;
        int y1 = (y0 + 1 > H - 1) ? H - 1 : y0 + 1;
        int z1 = (z0 + 1 > D - 1) ? D - 1 : z0 + 1;

        float ux = 1.0f - wx, uy = 1.0f - wy, uz = 1.0f - wz;
        float w[8] = { uz * uy * ux, uz * uy * wx, uz * wy * ux, uz * wy * wx,
                       wz * uy * ux, wz * uy * wx, wz * wy * ux, wz * wy * wx };

        int r00 = (z0 * H + y0) * W;
        int r01 = (z0 * H + y1) * W;
        int r10 = (z1 * H + y0) * W;
        int r11 = (z1 * H + y1) * W;
        int o[8] = { r00 + x0, r00 + x1, r01 + x0, r01 + x1,
                     r10 + x0, r10 + x1, r11 + x0, r11 + x1 };

        #pragma unroll
        for (int cn = 0; cn < 8; cn++) {
            float wt = w[cn];
            const float* sp = src + o[cn];
            #pragma unroll
            for (int c = 0; c < NCH; c++)
                acc[c] = fmaf(wt, sp[(size_t)c * WS_P], acc[c]);
        }
    }

    float* op = out + (size_t)I * NCH * WS_P + p;
    #pragma unroll
    for (int c = 0; c < NCH; c++) op[(size_t)c * WS_P] = acc[c];
}

extern "C" void kernel_launch(void* const* d_in, const int* in_sizes, int n_in,
                              void* d_out, int out_size, void* d_ws, size_t ws_size,
                              hipStream_t stream) {
    const float* f0 = (const float*)d_in[0];
    const float* f1 = (const float*)d_in[1];
    const float* f2 = (const float*)d_in[2];
    const float* v0 = (const float*)d_in[3];
    const float* v1 = (const float*)d_in[4];
    const float* v2 = (const float*)d_in[5];
    float* out = (float*)d_out;

    char* ws = (char*)d_ws;
    const size_t FEAT_ELEMS = (size_t)NCH * WS_P;        // 16 M
    const size_t MB = 1u << 20;
    unsigned* mm = (unsigned*)ws;                        // 256 B
    unsigned* tot = (unsigned*)(ws + 4096);              // 6 KB
    unsigned* binbase = (unsigned*)(ws + 16384);         // 6 KB
    __half* t0 = (__half*)(ws + MB);                     // 3 x 32 MB
    __half* t1 = t0 + FEAT_ELEMS;
    __half* t2 = t1 + FEAT_ELEMS;
    size_t off = MB + 3 * FEAT_ELEMS * sizeof(__half);
    uint4* rec = (uint4*)(ws + off);       off += 3 * (size_t)WS_P * 16;  // 24 MB
    unsigned* counts = (unsigned*)(ws + off);
    off += (size_t)3 * NBLK * NBIN * 4;                                   // 1.5 MB
    __half* temps = (__half*)(ws + off);
    off += 3 * FEAT_ELEMS * sizeof(__half);                               // 96 MB
    const size_t FULL_NEED = off;
    const size_t MID_NEED = MB + 3 * FEAT_ELEMS * sizeof(__half);

    hipLaunchKernelGGL(init_mm_kernel, dim3(1), dim3(32), 0, stream, mm);
    hipLaunchKernelGGL(minmax_kernel, dim3(128, 3), dim3(256), 0, stream,
                       v0, v1, v2, mm);

    if (ws_size >= FULL_NEED) {
        hipLaunchKernelGGL(transpose_hist_kernel, dim3(NBLK + NTB, 3), dim3(256),
                           0, stream, f0, f1, f2, t0, t1, t2,
                           v0, v1, v2, mm, counts);
        hipLaunchKernelGGL(scanA_kernel, dim3(NBIN, 3), dim3(NBLK), 0, stream,
                           counts, tot);
        hipLaunchKernelGGL(scanB_kernel, dim3(3), dim3(NBIN), 0, stream,
                           tot, binbase);
        hipLaunchKernelGGL(scatter_kernel, dim3(NBLK, 3), dim3(256), 0, stream,
                           v0, v1, v2, mm, counts, binbase, rec);
        hipLaunchKernelGGL(sample_all_kernel, dim3(NSB, 3), dim3(256), 0,
                           stream, t0, t1, t2, rec, temps);
        hipLaunchKernelGGL(finish_kernel, dim3(WS_P / 32, 3), dim3(256), 0,
                           stream, temps, t0, t1, t2, out);
    } else if (ws_size >= MID_NEED) {
        hipLaunchKernelGGL(transpose16_kernel, dim3(NTB, 3), dim3(256), 0,
                           stream, f0, f1, f2, t0, t1, t2);
        hipLaunchKernelGGL(fused_sample_kernel, dim3(WS_P / 32, 3), dim3(256), 0,
                           stream, t0, t1, t2, v0, v1, v2, mm, out);
    } else {
        hipLaunchKernelGGL((sample_fallback_kernel<0>), dim3(WS_P / 256), dim3(256), 0,
                           stream, f0, f1, f2, v0, v1, v2, mm, out);
        hipLaunchKernelGGL((sample_fallback_kernel<1>), dim3(WS_P / 256), dim3(256), 0,
                           stream, f0, f1, f2, v0, v1, v2, mm, out);
        hipLaunchKernelGGL((sample_fallback_kernel<2>), dim3(WS_P / 256), dim3(256), 0,
                           stream, f0, f1, f2, v0, v1, v2, mm, out);
    }
}